// Round 6
// baseline (1228.047 us; speedup 1.0000x reference)
//
#include <hip/hip_runtime.h>
#include <cmath>

// GaussCRF on MI355X — round 13: persistent kernel, manual grid barrier.
// B=2, C=21, H=W=512, blur=4 -> h=w=128, K=11 (121 shifts), 5 iterations.
//
// r12 post-mortem: cooperative launch killed the container; code audit found
// no logic bug -> prime suspect is hipLaunchCooperativeKernel under the
// harness's graph capture. r13 keeps the single-kernel structure (r11 budget:
// ~90us launch gaps + ~15us g round-trip are the remaining sinks) but uses:
//  * plain hipLaunchKernelGGL (capture-safe) at 512 blocks x 256 thr
//    (2 blocks/CU guaranteed: 55.5 KB LDS, VGPR<=128 via launch_bounds);
//  * a manual device-scope atomic barrier in workspace (same mechanism
//    cg::grid_group::sync uses internally), counters zeroed by a captured
//    hipMemsetAsync (workspace is poisoned between runs);
//  * g computed once to workspace (r9 gauss verbatim) and re-loaded per
//    iteration (r11-proven pattern) to keep VGPR pressure low.
// All per-element arithmetic orders identical to r10/r11 -> absmax 0.25.

#define BB 2
#define CC 21
#define HH 512
#define WW 512
#define HP 128
#define WP 128
#define KF 11
#define SPAN 5
#define NITER 5
#define PLF (HH*WW)
#define PLP (HP*WP)
#define PC 24      // packed channel stride (floats), 96 B = 6 x float4
#define LSTR 28    // halo LDS stride in floats (balanced: 8 lanes/bank-quad)
#define RSTR 25    // reduce-buffer lane stride (odd -> conflict-free)
#define PT_N (18*18*LSTR)          // 9072 floats
#define SH_N (PT_N + 3*64*RSTR)    // 13872 floats = 55.5 KB
#define NBLK 512

__device__ __forceinline__ void gbar(unsigned* cnt, unsigned* gen, int tid) {
    __syncthreads();
    if (tid == 0) {
        __threadfence();                       // publish this block's writes
        unsigned g = __hip_atomic_load(gen, __ATOMIC_ACQUIRE,
                                       __HIP_MEMORY_SCOPE_AGENT);
        unsigned a = __hip_atomic_fetch_add(cnt, 1u, __ATOMIC_ACQ_REL,
                                            __HIP_MEMORY_SCOPE_AGENT);
        if (a == NBLK - 1u) {
            __hip_atomic_store(cnt, 0u, __ATOMIC_RELAXED,
                               __HIP_MEMORY_SCOPE_AGENT);
            __hip_atomic_fetch_add(gen, 1u, __ATOMIC_RELEASE,
                                   __HIP_MEMORY_SCOPE_AGENT);
        } else {
            while (__hip_atomic_load(gen, __ATOMIC_ACQUIRE,
                                     __HIP_MEMORY_SCOPE_AGENT) == g)
                __builtin_amdgcn_s_sleep(1);
        }
        __threadfence();                       // import other blocks' writes
    }
    __syncthreads();
}

__global__ __launch_bounds__(256, 2) void crf_k(
    const float* __restrict__ unary, const float* __restrict__ img,
    const float* __restrict__ pos_sdims, const float* __restrict__ col_schan,
    const float* __restrict__ pos_compat, const float* __restrict__ col_compat,
    const float* __restrict__ weight,
    unsigned* __restrict__ bar,
    float* __restrict__ cf, float* __restrict__ g, float* __restrict__ msgb,
    float* __restrict__ pA, float* __restrict__ pB,
    float* __restrict__ pred)
{
    __shared__ __align__(16) float sh[SH_N];
    unsigned* bcnt = bar;
    unsigned* bgen = bar + 1;
    const int bid = blockIdx.x;          // 0..511
    const int t = threadIdx.x;           // 0..255
    const int w = t >> 6, lane = t & 63;
    const int px = lane >> 3, py = lane & 7;   // position in 8x8 msg tile
    const int gb = bid >> 8;                   // msg-tile batch
    const int tX = (bid >> 4) & 15, tY = bid & 15;

    // ---------------- Phase A: pool img -> cf; init p0 -> pA ----------------
    {
        int idx = bid*256 + t;
        if (idx < BB*3*PLP) {
            int Y  = idx & (WP-1);
            int X  = (idx >> 7) & (HP-1);
            int bc = idx >> 14;
            const float* base = img + ((size_t)bc*HH + X*4)*WW + Y*4;
            float s = 0.f;
            #pragma unroll
            for (int i = 0; i < 4; ++i)
                #pragma unroll
                for (int j = 0; j < 4; ++j)
                    s += base[i*WW + j];
            cf[idx] = s * (1.f/16.f) * col_schan[0];
        }
    }
    #pragma unroll
    for (int half = 0; half < 2; ++half) {
        int tid = bid + half*512;            // 1024 init tiles
        int b = tid >> 9, rem = tid & 511, tx = rem >> 4, ty = rem & 15;
        int irow = t >> 4, ic2 = t & 15;
        int ix = tx*16 + irow, iy = ty*32 + 2*ic2;
        size_t base = (size_t)b*CC*PLF + (size_t)ix*WW + iy;
        float va[CC], vb[CC];
        float ma = -1e30f, mb = -1e30f;
        #pragma unroll
        for (int c = 0; c < CC; ++c) {
            float2 u = *(const float2*)(unary + base + (size_t)c*PLF);
            va[c] = u.x; vb[c] = u.y;
            ma = fmaxf(ma, u.x); mb = fmaxf(mb, u.y);
        }
        float sa = 0.f, sb = 0.f;
        #pragma unroll
        for (int c = 0; c < CC; ++c) { sa += expf(va[c]-ma); sb += expf(vb[c]-mb); }
        float lsa = ma + logf(sa), lsb = mb + logf(sb);
        float out[PC];
        #pragma unroll
        for (int c = 0; c < PC; ++c) out[c] = 0.f;
        #pragma unroll
        for (int c = 0; c < CC; ++c) {
            float sm = (va[c]-lsa) + (vb[c]-lsb);
            sm += __shfl_xor(sm, 1);
            sm += __shfl_xor(sm, 16);
            sm += __shfl_xor(sm, 32);
            out[c] = sm * (1.f/16.f);
        }
        if ((lane & 49) == 0) {              // bits {0,4,5} == 0
            int X = tx*4 + (t >> 6), Y = ty*8 + (ic2 >> 1);
            float4* dst = (float4*)(pA + ((size_t)(b*HP + X)*WP + Y)*PC);
            const float4* src = (const float4*)out;
            dst[0]=src[0]; dst[1]=src[1]; dst[2]=src[2];
            dst[3]=src[3]; dst[4]=src[4]; dst[5]=src[5];
        }
    }
    gbar(bcnt, bgen, t);

    // ---- Phase A2: g for this block's tile -> workspace (block-tiled) ----
    {
        const float* cb = cf + (size_t)gb*3*PLP;
        const float ps  = 4.f * pos_sdims[0];
        const float pcm = pos_compat[0], ccm = col_compat[0];
        for (int e = t; e < 121*64; e += 256) {
            int pos = e & 63;
            int ij  = e >> 6;
            int X = tX*8 + (pos >> 3), Y = tY*8 + (pos & 7);
            int di = ij / KF - SPAN;
            int dj = ij % KF - SPAN;
            int Xn = X + di, Yn = Y + dj;
            float val = 0.f;
            if (Xn >= 0 && Xn < HP && Yn >= 0 && Yn < WP) {
                int o0 = X*WP + Y, o = Xn*WP + Yn;
                float d0 = cb[o]         - cb[o0];
                float d1 = cb[PLP + o]   - cb[PLP + o0];
                float d2 = cb[2*PLP + o] - cb[2*PLP + o0];
                float cd2 = d0*d0 + d1*d1 + d2*d2;
                float pd2 = ps*ps * (float)(di*di + dj*dj);
                val = pcm * expf(-0.5f*pd2) + ccm * expf(-0.5f*cd2);
            }
            g[(size_t)bid*(121*64) + e] = val;
        }
    }
    gbar(bcnt, bgen, t);

    // ---------------- iterations ----------------
    const float wt = weight[0], uw = 1.f - wt;   // UNARY_WEIGHT = 1.0
    for (int it = 0; it < NITER; ++it) {
        const float* pcur = (it & 1) ? pB : pA;
        float* pnew       = (it & 1) ? pA : pB;
        const int last = (it == NITER-1);

        // ---- Phase C: msg for this block's 8x8 tile ----
        {
            // g prefetch (r11 pattern: issue before staging)
            const float* gt = g + (size_t)bid*(121*64) + lane;
            const int row0 = w*3, row1 = w*3 + 1;
            const int row2 = (w == 3) ? 10 : w*3 + 2;
            const float gm = (w == 3) ? 0.f : 1.f;
            float gvals[33];
            #pragma unroll
            for (int dj = 0; dj < KF; ++dj)
                gvals[dj]      = gt[(size_t)(row0*KF + dj) * 64];
            #pragma unroll
            for (int dj = 0; dj < KF; ++dj)
                gvals[11 + dj] = gt[(size_t)(row1*KF + dj) * 64];
            #pragma unroll
            for (int dj = 0; dj < KF; ++dj)
                gvals[22 + dj] = gt[(size_t)(row2*KF + dj) * 64] * gm;

            float* pt = sh;
            int X0 = tX*8 - SPAN, Y0 = tY*8 - SPAN;
            const float4* pg = (const float4*)(pcur + (size_t)gb*PLP*PC);
            for (int e = t; e < 18*18*6; e += 256) {
                int pos = e / 6, k = e % 6;
                int r = pos / 18, cl = pos % 18;
                int gX = X0 + r, gY = Y0 + cl;
                float4 v = {0.f,0.f,0.f,0.f};
                if (gX >= 0 && gX < HP && gY >= 0 && gY < WP)
                    v = pg[(size_t)(gX*WP + gY)*6 + k];
                *(float4*)(pt + pos*LSTR + k*4) = v;
            }
            __syncthreads();
            const int rows[3] = {row0, row1, row2};
            float acc[CC];
            #pragma unroll
            for (int c = 0; c < CC; ++c) acc[c] = 0.f;
            #pragma unroll
            for (int r = 0; r < 3; ++r) {
                const float* prow = pt + ((px + rows[r])*18 + py)*LSTR;
                #pragma unroll
                for (int dj = 0; dj < KF; ++dj) {
                    float gv = gvals[r*11 + dj];
                    const float4* sp = (const float4*)(prow + dj*LSTR);
                    float4 q0 = sp[0], q1 = sp[1], q2 = sp[2];
                    float4 q3 = sp[3], q4 = sp[4], q5 = sp[5];
                    acc[0]  = fmaf(gv, q0.x, acc[0]);  acc[1]  = fmaf(gv, q0.y, acc[1]);
                    acc[2]  = fmaf(gv, q0.z, acc[2]);  acc[3]  = fmaf(gv, q0.w, acc[3]);
                    acc[4]  = fmaf(gv, q1.x, acc[4]);  acc[5]  = fmaf(gv, q1.y, acc[5]);
                    acc[6]  = fmaf(gv, q1.z, acc[6]);  acc[7]  = fmaf(gv, q1.w, acc[7]);
                    acc[8]  = fmaf(gv, q2.x, acc[8]);  acc[9]  = fmaf(gv, q2.y, acc[9]);
                    acc[10] = fmaf(gv, q2.z, acc[10]); acc[11] = fmaf(gv, q2.w, acc[11]);
                    acc[12] = fmaf(gv, q3.x, acc[12]); acc[13] = fmaf(gv, q3.y, acc[13]);
                    acc[14] = fmaf(gv, q3.z, acc[14]); acc[15] = fmaf(gv, q3.w, acc[15]);
                    acc[16] = fmaf(gv, q4.x, acc[16]); acc[17] = fmaf(gv, q4.y, acc[17]);
                    acc[18] = fmaf(gv, q4.z, acc[18]); acc[19] = fmaf(gv, q4.w, acc[19]);
                    acc[20] = fmaf(gv, q5.x, acc[20]);
                }
            }
            float* rb = sh + PT_N;               // [3][64][RSTR]
            if (w > 0) {
                #pragma unroll
                for (int c = 0; c < CC; ++c)
                    rb[((w-1)*64 + lane)*RSTR + c] = acc[c];
            }
            __syncthreads();
            if (w == 0) {
                int Xg = tX*8 + px, Yg = tY*8 + py;
                float* mb = msgb + (size_t)gb*CC*PLP + (size_t)Xg*WP + Yg;
                #pragma unroll
                for (int c = 0; c < CC; ++c) {
                    float s = ((acc[c] + rb[(0*64 + lane)*RSTR + c])
                                      + rb[(1*64 + lane)*RSTR + c])
                                      + rb[(2*64 + lane)*RSTR + c];
                    mb[(size_t)c*PLP] = s;
                }
            }
        }
        gbar(bcnt, bgen, t);

        // ---- Phase D: combine, 2 tiles per block ----
        for (int half = 0; half < 2; ++half) {
            __syncthreads();                     // sh reuse guard
            int tid = bid + half*512;
            int b2 = tid >> 9, rem = tid & 511, tx2 = rem >> 4, ty2 = rem & 15;
            float* ms = sh;                      // [CC][6][10] -> c*60+rr*10+cl
            const float* mbp = msgb + (size_t)b2*CC*PLP;
            for (int e = t; e < CC*60; e += 256) {
                int c = e / 60, rr = (e / 10) % 6, cl = e % 10;
                int gX = tx2*4 - 1 + rr; gX = gX < 0 ? 0 : (gX > HP-1 ? HP-1 : gX);
                int gY = ty2*8 - 1 + cl; gY = gY < 0 ? 0 : (gY > WP-1 ? WP-1 : gY);
                ms[c*60 + rr*10 + cl] = mbp[(size_t)c*PLP + gX*WP + gY];
            }
            __syncthreads();
            int crow = t >> 4, cc2 = t & 15;
            int cx = tx2*16 + crow, cy = ty2*32 + 2*cc2;
            size_t base = (size_t)b2*CC*PLF + (size_t)cx*WW + cy;
            int rs = crow & 3, q = crow >> 2;
            float fx = (rs == 0) ? 0.625f : (rs == 1) ? 0.875f
                     : (rs == 2) ? 0.125f : 0.375f;
            int i0 = q + (rs >> 1);
            int cs0 = (2*cc2) & 3;
            int qc  = (2*cc2) >> 2;
            float fya = (cs0 == 0) ? 0.625f : 0.125f;
            float fyb = (cs0 == 0) ? 0.875f : 0.375f;
            int j0 = qc + (cs0 >> 1);
            float gx0 = 1.f - fx;
            float va[CC], vb[CC];
            float ma = -1e30f, mbx = -1e30f;
            #pragma unroll
            for (int c = 0; c < CC; ++c) {
                float2 u = *(const float2*)(unary + base + (size_t)c*PLF);
                va[c] = u.x; vb[c] = u.y;
                ma = fmaxf(ma, u.x); mbx = fmaxf(mbx, u.y);
            }
            float sa = 0.f, sb = 0.f;
            #pragma unroll
            for (int c = 0; c < CC; ++c) { sa += expf(va[c]-ma); sb += expf(vb[c]-mbx); }
            float lsa = ma + logf(sa), lsb = mbx + logf(sb);
            #pragma unroll
            for (int c = 0; c < CC; ++c) {
                float m00 = ms[c*60 + i0*10 + j0],     m01 = ms[c*60 + i0*10 + j0+1];
                float m10 = ms[c*60 + (i0+1)*10 + j0], m11 = ms[c*60 + (i0+1)*10 + j0+1];
                float ca = gx0*m00 + fx*m10;
                float cb = gx0*m01 + fx*m11;
                float mua = (1.f-fya)*ca + fya*cb;
                float mub = (1.f-fyb)*ca + fyb*cb;
                va[c] = uw*(va[c]-lsa) + wt*mua;
                vb[c] = uw*(vb[c]-lsb) + wt*mub;
            }
            if (last) {
                #pragma unroll
                for (int c = 0; c < CC; ++c) {
                    float2 o; o.x = va[c]; o.y = vb[c];
                    *(float2*)(pred + base + (size_t)c*PLF) = o;
                }
            } else {
                float mma = -1e30f, mmb = -1e30f;
                #pragma unroll
                for (int c = 0; c < CC; ++c) { mma = fmaxf(mma, va[c]); mmb = fmaxf(mmb, vb[c]); }
                float ssa = 0.f, ssb = 0.f;
                #pragma unroll
                for (int c = 0; c < CC; ++c) {
                    va[c] = expf(va[c]-mma); ssa += va[c];
                    vb[c] = expf(vb[c]-mmb); ssb += vb[c];
                }
                float ia = 1.f/ssa, ib = 1.f/ssb;
                float out[PC];
                #pragma unroll
                for (int c = 0; c < PC; ++c) out[c] = 0.f;
                #pragma unroll
                for (int c = 0; c < CC; ++c) {
                    float sm = va[c]*ia + vb[c]*ib;
                    sm += __shfl_xor(sm, 1);
                    sm += __shfl_xor(sm, 16);
                    sm += __shfl_xor(sm, 32);
                    out[c] = sm * (1.f/16.f);
                }
                if ((lane & 49) == 0) {
                    int X = tx2*4 + (t >> 6), Y = ty2*8 + (cc2 >> 1);
                    float4* dst = (float4*)(pnew + ((size_t)(b2*HP + X)*WP + Y)*PC);
                    const float4* src = (const float4*)out;
                    dst[0]=src[0]; dst[1]=src[1]; dst[2]=src[2];
                    dst[3]=src[3]; dst[4]=src[4]; dst[5]=src[5];
                }
            }
        }
        if (!last) gbar(bcnt, bgen, t);
    }
}

extern "C" void kernel_launch(void* const* d_in, const int* in_sizes, int n_in,
                              void* d_out, int out_size, void* d_ws, size_t ws_size,
                              hipStream_t stream) {
    const float* unary      = (const float*)d_in[0];
    const float* img        = (const float*)d_in[1];
    const float* pos_sdims  = (const float*)d_in[2];
    const float* col_schan  = (const float*)d_in[3];
    const float* pos_compat = (const float*)d_in[4];
    const float* col_compat = (const float*)d_in[5];
    const float* weight     = (const float*)d_in[6];
    float* pred = (float*)d_out;
    float* ws   = (float*)d_ws;

    unsigned* bar = (unsigned*)ws;               // ws[0..3]: cnt, gen (+pad)
    size_t o = 16;                               // 64 B aligned
    float* cf   = ws + o;  o += (size_t)BB*3*PLP;    // 0.4 MB
    float* g    = ws + o;  o += (size_t)BB*121*PLP;  // 15.9 MB (block-tiled)
    float* msgb = ws + o;  o += (size_t)BB*CC*PLP;   // 2.75 MB
    float* pA   = ws + o;  o += (size_t)BB*PLP*PC;   // 3.1 MB packed
    float* pB   = ws + o;  o += (size_t)BB*PLP*PC;   // 3.1 MB packed

    hipMemsetAsync(bar, 0, 16, stream);          // barrier state (ws poisoned)
    hipLaunchKernelGGL(crf_k, dim3(NBLK), dim3(256), 0, stream,
                       unary, img, pos_sdims, col_schan, pos_compat,
                       col_compat, weight, bar, cf, g, msgb, pA, pB, pred);
}

// Round 7
// 267.896 us; speedup vs baseline: 4.5840x; 4.5840x over previous
//
#include <hip/hip_runtime.h>
#include <cmath>

// GaussCRF on MI355X — round 14.
// B=2, C=21, H=W=512, blur=4 -> h=w=128, K=11 (121 shifts), 5 iterations.
//
// r13 post-mortem: persistent kernel + manual grid barrier = 1159us, VALU 7%:
// device-scope fences on 8 non-coherent XCD L2s make every in-kernel grid
// barrier an L2 flush + cold restart (FETCH 239MB proves unary re-fetched
// each iter). Kernel launches ARE the cheapest grid barrier here. Reverted
// to r10 (271us best).
// r14 = r10 + two low-risk changes:
//  * msg_k: rbuf (19.2KB) OVERLAID on pt (36.3KB) — they're live in
//    disjoint phases (extra __syncthreads between pt-reads and rbuf-writes).
//    LDS 55.5 -> 36.3KB; LDS was the occupancy binder -> 4 blocks/CU
//    (16 waves/CU, was 8). No numeric change.
//  * pool_img + init_p fused into one partitioned-grid prep_k (independent
//    work) -> 12 dispatches (was 13).
// All arithmetic byte-identical to r10 -> absmax exactly 0.25.

#define BB 2
#define CC 21
#define HH 512
#define WW 512
#define HP 128
#define WP 128
#define KF 11
#define SPAN 5
#define NB 121
#define NITER 5
#define PLF (HH*WW)
#define PLP (HP*WP)
#define PC 24      // packed channel stride (floats), 96 B = 6 x float4
#define LSTR 28    // halo LDS stride in floats (balanced: 8 lanes/bank-quad)
#define RSTR 25    // reduce-buffer lane stride (odd -> conflict-free)
#define PT_N (18*18*LSTR)          // 9072 floats = 36.3 KB

// blocks 0..1023: init tiles; blocks 1024..1407: img pool.
__global__ __launch_bounds__(256) void prep_k(const float* __restrict__ img,
                                              const float* __restrict__ col_schan,
                                              const float* __restrict__ unary,
                                              float* __restrict__ cf,
                                              float* __restrict__ p) {
    int bid = blockIdx.x;
    int t = threadIdx.x;
    if (bid >= 1024) {                       // ---- pool img -> cf ----
        int idx = (bid - 1024)*256 + t;      // < BB*3*PLP = 98304 exactly
        int Y  = idx & (WP-1);
        int X  = (idx >> 7) & (HP-1);
        int bc = idx >> 14;
        const float* base = img + ((size_t)bc*HH + X*4)*WW + Y*4;
        float s = 0.f;
        #pragma unroll
        for (int i = 0; i < 4; ++i)
            #pragma unroll
            for (int j = 0; j < 4; ++j)
                s += base[i*WW + j];
        cf[idx] = s * (1.f/16.f) * col_schan[0];
        return;
    }
    // ---- p0 = 4x4 pool of log_softmax(unary), packed [b][X][Y][24] ----
    int b = bid >> 9, rem = bid & 511, tx = rem >> 4, ty = rem & 15;
    int row = t >> 4, c2 = t & 15;
    int x = tx*16 + row, y = ty*32 + 2*c2;
    size_t base = (size_t)b*CC*PLF + (size_t)x*WW + y;
    float va[CC], vb[CC];
    float ma = -1e30f, mb = -1e30f;
    #pragma unroll
    for (int c = 0; c < CC; ++c) {
        float2 u = *(const float2*)(unary + base + (size_t)c*PLF);
        va[c] = u.x; vb[c] = u.y;
        ma = fmaxf(ma, u.x); mb = fmaxf(mb, u.y);
    }
    float sa = 0.f, sb = 0.f;
    #pragma unroll
    for (int c = 0; c < CC; ++c) { sa += expf(va[c]-ma); sb += expf(vb[c]-mb); }
    float lsa = ma + logf(sa), lsb = mb + logf(sb);
    float out[PC];
    #pragma unroll
    for (int c = 0; c < PC; ++c) out[c] = 0.f;
    #pragma unroll
    for (int c = 0; c < CC; ++c) {
        float sm = (va[c]-lsa) + (vb[c]-lsb);
        sm += __shfl_xor(sm, 1);
        sm += __shfl_xor(sm, 16);
        sm += __shfl_xor(sm, 32);
        out[c] = sm * (1.f/16.f);
    }
    int lane = t & 63;
    if ((lane & 49) == 0) {                  // bits {0,4,5} == 0
        int X = tx*4 + (t >> 6), Y = ty*8 + (c2 >> 1);
        float4* dst = (float4*)(p + ((size_t)(b*HP + X)*WP + Y)*PC);
        const float4* src = (const float4*)out;
        dst[0]=src[0]; dst[1]=src[1]; dst[2]=src[2];
        dst[3]=src[3]; dst[4]=src[4]; dst[5]=src[5];
    }
}

// g block-tiled: g[((b*16+tX)*16+tY)*121*64 + ij*64 + pos], pos = 8x8 tile.
__global__ void gauss_k(const float* __restrict__ cf,
                        const float* __restrict__ pos_sdims,
                        const float* __restrict__ pos_compat,
                        const float* __restrict__ col_compat,
                        float* __restrict__ g) {
    int tile = blockIdx.y;
    int e = blockIdx.x * blockDim.x + threadIdx.x;
    if (e >= NB*64) return;
    int pos = e & 63;
    int ij  = e >> 6;
    int tY = tile & 15, tX = (tile >> 4) & 15, b = tile >> 8;
    int X = tX*8 + (pos >> 3), Y = tY*8 + (pos & 7);
    int di = ij / KF - SPAN;
    int dj = ij % KF - SPAN;
    int Xn = X + di, Yn = Y + dj;
    float val = 0.f;
    if (Xn >= 0 && Xn < HP && Yn >= 0 && Yn < WP) {
        const float* cb = cf + (size_t)b*3*PLP;
        int o0 = X*WP + Y, o = Xn*WP + Yn;
        float d0 = cb[o]         - cb[o0];
        float d1 = cb[PLP + o]   - cb[PLP + o0];
        float d2 = cb[2*PLP + o] - cb[2*PLP + o0];
        float cd2 = d0*d0 + d1*d1 + d2*d2;
        float ps  = 4.f * pos_sdims[0];
        float pd2 = ps*ps * (float)(di*di + dj*dj);
        val = pos_compat[0] * expf(-0.5f*pd2) + col_compat[0] * expf(-0.5f*cd2);
    }
    g[(size_t)tile*NB*64 + e] = val;
}

// msg[b,c,X,Y] = sum_ij g[b,ij,X,Y] * p_packed[b,X+di-5,Y+dj-5,c]
// 256 thr = 4 waves, channel-major; wave w owns di rows {0-2,3-5,6-8,9-10}.
// rbuf overlaid on pt (disjoint live ranges) -> LDS 36.3KB, 4 blocks/CU.
__global__ __launch_bounds__(256) void msg_k(const float* __restrict__ g,
                                             const float* __restrict__ p,
                                             float* __restrict__ msg) {
    int b = blockIdx.z, tx = blockIdx.y, ty = blockIdx.x;
    int t = threadIdx.x;
    __shared__ __align__(16) float sh[PT_N];           // 36.3 KB total
    float* pt = sh;
    int X0 = tx*8 - SPAN, Y0 = ty*8 - SPAN;
    const float4* pg = (const float4*)(p + (size_t)b*PLP*PC);
    for (int e = t; e < 18*18*6; e += 256) {
        int pos = e / 6, k = e % 6;
        int r = pos / 18, cl = pos % 18;
        int gX = X0 + r, gY = Y0 + cl;
        float4 v = {0.f,0.f,0.f,0.f};
        if (gX >= 0 && gX < HP && gY >= 0 && gY < WP)
            v = pg[(size_t)(gX*WP + gY)*6 + k];
        *(float4*)(pt + pos*LSTR + k*4) = v;
    }
    __syncthreads();
    int w = t >> 6, lane = t & 63;
    int x = lane >> 3, y = lane & 7;
    const float* gt = g + (size_t)((b*16 + tx)*16 + ty)*NB*64 + lane;
    int d0 = w*3, d1 = (w == 3) ? KF : w*3 + 3;        // {0-2,3-5,6-8,9-10}
    float acc[CC];
    #pragma unroll
    for (int c = 0; c < CC; ++c) acc[c] = 0.f;
    for (int di = d0; di < d1; ++di) {
        const float* prow = pt + ((x+di)*18 + y)*LSTR;
        const float* grow = gt + (size_t)(di*KF)*64;
        #pragma unroll
        for (int dj = 0; dj < KF; ++dj) {
            float gv = grow[(size_t)dj*64];
            const float4* sp = (const float4*)(prow + dj*LSTR);
            float4 q0 = sp[0], q1 = sp[1], q2 = sp[2];
            float4 q3 = sp[3], q4 = sp[4], q5 = sp[5];
            acc[0]  = fmaf(gv, q0.x, acc[0]);  acc[1]  = fmaf(gv, q0.y, acc[1]);
            acc[2]  = fmaf(gv, q0.z, acc[2]);  acc[3]  = fmaf(gv, q0.w, acc[3]);
            acc[4]  = fmaf(gv, q1.x, acc[4]);  acc[5]  = fmaf(gv, q1.y, acc[5]);
            acc[6]  = fmaf(gv, q1.z, acc[6]);  acc[7]  = fmaf(gv, q1.w, acc[7]);
            acc[8]  = fmaf(gv, q2.x, acc[8]);  acc[9]  = fmaf(gv, q2.y, acc[9]);
            acc[10] = fmaf(gv, q2.z, acc[10]); acc[11] = fmaf(gv, q2.w, acc[11]);
            acc[12] = fmaf(gv, q3.x, acc[12]); acc[13] = fmaf(gv, q3.y, acc[13]);
            acc[14] = fmaf(gv, q3.z, acc[14]); acc[15] = fmaf(gv, q3.w, acc[15]);
            acc[16] = fmaf(gv, q4.x, acc[16]); acc[17] = fmaf(gv, q4.y, acc[17]);
            acc[18] = fmaf(gv, q4.z, acc[18]); acc[19] = fmaf(gv, q4.w, acc[19]);
            acc[20] = fmaf(gv, q5.x, acc[20]);
        }
    }
    __syncthreads();                       // all pt reads done before overlay
    float* rb = sh;                        // rbuf [3][64][RSTR] overlays pt
    if (w > 0) {
        #pragma unroll
        for (int c = 0; c < CC; ++c) rb[((w-1)*64 + lane)*RSTR + c] = acc[c];
    }
    __syncthreads();
    if (w == 0) {
        int Xg = tx*8 + x, Yg = ty*8 + y;
        float* mb = msg + (size_t)b*CC*PLP + (size_t)Xg*WP + Yg;
        #pragma unroll
        for (int c = 0; c < CC; ++c) {
            float s = ((acc[c] + rb[(0*64 + lane)*RSTR + c])
                              + rb[(1*64 + lane)*RSTR + c])
                              + rb[(2*64 + lane)*RSTR + c];
            mb[(size_t)c*PLP] = s;
        }
    }
}

// bilinear 4x upsample of msg + 0.8*lg + 0.2*mu; iters 0..3: softmax + 4x4
// pool -> packed p; last iter: write fp32 pred. 2 pixels per thread.
__global__ __launch_bounds__(256) void combine_k(const float* __restrict__ msg,
                                                 const float* __restrict__ unary,
                                                 const float* __restrict__ weight,
                                                 float* __restrict__ pnew,
                                                 float* __restrict__ pred,
                                                 int last) {
    int b = blockIdx.z, tx = blockIdx.y, ty = blockIdx.x;
    int t = threadIdx.x;
    __shared__ float ms[CC][6][10];
    const float* mb = msg + (size_t)b*CC*PLP;
    for (int e = t; e < CC*60; e += 256) {
        int c = e / 60, rr = (e / 10) % 6, cl = e % 10;
        int gX = tx*4 - 1 + rr; gX = gX < 0 ? 0 : (gX > HP-1 ? HP-1 : gX);
        int gY = ty*8 - 1 + cl; gY = gY < 0 ? 0 : (gY > WP-1 ? WP-1 : gY);
        ms[c][rr][cl] = mb[(size_t)c*PLP + gX*WP + gY];
    }
    __syncthreads();
    int row = t >> 4, c2 = t & 15;
    int x = tx*16 + row, y = ty*32 + 2*c2;
    size_t base = (size_t)b*CC*PLF + (size_t)x*WW + y;
    // bilinear: fx per (x%4): {0.625, 0.875, 0.125, 0.375}
    int rs = row & 3, q = row >> 2;
    float fx = (rs == 0) ? 0.625f : (rs == 1) ? 0.875f : (rs == 2) ? 0.125f : 0.375f;
    int i0 = q + (rs >> 1);
    int cs0 = (2*c2) & 3;                    // 0 or 2; pixel pair shares j0
    int qc  = (2*c2) >> 2;
    float fya = (cs0 == 0) ? 0.625f : 0.125f;
    float fyb = (cs0 == 0) ? 0.875f : 0.375f;
    int j0 = qc + (cs0 >> 1);
    float gx0 = 1.f - fx;
    float wt = weight[0], uw = 1.f - wt;     // UNARY_WEIGHT = 1.0
    float va[CC], vb[CC];
    float ma = -1e30f, mbx = -1e30f;
    #pragma unroll
    for (int c = 0; c < CC; ++c) {
        float2 u = *(const float2*)(unary + base + (size_t)c*PLF);
        va[c] = u.x; vb[c] = u.y;
        ma = fmaxf(ma, u.x); mbx = fmaxf(mbx, u.y);
    }
    float sa = 0.f, sb = 0.f;
    #pragma unroll
    for (int c = 0; c < CC; ++c) { sa += expf(va[c]-ma); sb += expf(vb[c]-mbx); }
    float lsa = ma + logf(sa), lsb = mbx + logf(sb);
    #pragma unroll
    for (int c = 0; c < CC; ++c) {
        float m00 = ms[c][i0][j0],   m01 = ms[c][i0][j0+1];
        float m10 = ms[c][i0+1][j0], m11 = ms[c][i0+1][j0+1];
        float ca = gx0*m00 + fx*m10;         // column j0 blended in x
        float cb = gx0*m01 + fx*m11;         // column j0+1 blended in x
        float mua = (1.f-fya)*ca + fya*cb;
        float mub = (1.f-fyb)*ca + fyb*cb;
        va[c] = uw*(va[c]-lsa) + wt*mua;
        vb[c] = uw*(vb[c]-lsb) + wt*mub;
    }
    if (last) {
        #pragma unroll
        for (int c = 0; c < CC; ++c) {
            float2 o; o.x = va[c]; o.y = vb[c];
            *(float2*)(pred + base + (size_t)c*PLF) = o;
        }
    } else {
        float mma = -1e30f, mmb = -1e30f;
        #pragma unroll
        for (int c = 0; c < CC; ++c) { mma = fmaxf(mma, va[c]); mmb = fmaxf(mmb, vb[c]); }
        float ssa = 0.f, ssb = 0.f;
        #pragma unroll
        for (int c = 0; c < CC; ++c) {
            va[c] = expf(va[c]-mma); ssa += va[c];
            vb[c] = expf(vb[c]-mmb); ssb += vb[c];
        }
        float ia = 1.f/ssa, ib = 1.f/ssb;
        float out[PC];
        #pragma unroll
        for (int c = 0; c < PC; ++c) out[c] = 0.f;
        #pragma unroll
        for (int c = 0; c < CC; ++c) {
            float sm = va[c]*ia + vb[c]*ib;
            sm += __shfl_xor(sm, 1);
            sm += __shfl_xor(sm, 16);
            sm += __shfl_xor(sm, 32);
            out[c] = sm * (1.f/16.f);
        }
        int lane = t & 63;
        if ((lane & 49) == 0) {
            int X = tx*4 + (t >> 6), Y = ty*8 + (c2 >> 1);
            float4* dst = (float4*)(pnew + ((size_t)(b*HP + X)*WP + Y)*PC);
            const float4* src = (const float4*)out;
            dst[0]=src[0]; dst[1]=src[1]; dst[2]=src[2];
            dst[3]=src[3]; dst[4]=src[4]; dst[5]=src[5];
        }
    }
}

extern "C" void kernel_launch(void* const* d_in, const int* in_sizes, int n_in,
                              void* d_out, int out_size, void* d_ws, size_t ws_size,
                              hipStream_t stream) {
    const float* unary      = (const float*)d_in[0];
    const float* img        = (const float*)d_in[1];
    const float* pos_sdims  = (const float*)d_in[2];
    const float* col_schan  = (const float*)d_in[3];
    const float* pos_compat = (const float*)d_in[4];
    const float* col_compat = (const float*)d_in[5];
    const float* weight     = (const float*)d_in[6];
    float* pred = (float*)d_out;
    float* ws   = (float*)d_ws;

    size_t o = 0;
    float* cf  = ws + o;  o += (size_t)BB*3*PLP;     // 0.4 MB
    float* g   = ws + o;  o += (size_t)BB*NB*PLP;    // 15.9 MB (tiled)
    float* msg = ws + o;  o += (size_t)BB*CC*PLP;    // 2.75 MB
    float* pA  = ws + o;  o += (size_t)BB*PLP*PC;    // 3.1 MB packed
    float* pB  = ws + o;
    float* pbuf[2] = {pA, pB};

    const int TB = 256;
    hipLaunchKernelGGL(prep_k, dim3(1408), dim3(TB), 0, stream,
                       img, col_schan, unary, cf, pA);
    hipLaunchKernelGGL(gauss_k, dim3((NB*64+TB-1)/TB, 512), dim3(TB), 0, stream,
                       cf, pos_sdims, pos_compat, col_compat, g);
    for (int it = 0; it < NITER; ++it) {
        hipLaunchKernelGGL(msg_k, dim3(16, 16, BB), dim3(256), 0, stream,
                           g, pbuf[it & 1], msg);
        hipLaunchKernelGGL(combine_k, dim3(16, 32, BB), dim3(256), 0, stream,
                           msg, unary, weight, pbuf[(it + 1) & 1],
                           pred, (it == NITER-1) ? 1 : 0);
    }
}

// Round 8
// 262.134 us; speedup vs baseline: 4.6848x; 1.0220x over previous
//
#include <hip/hip_runtime.h>
#include <cmath>

// GaussCRF on MI355X — round 15.
// B=2, C=21, H=W=512, blur=4 -> h=w=128, K=11 (121 shifts), 5 iterations.
//
// r14 post-mortem: occupancy CAPACITY went to 4 blocks/CU but msg_k's grid
// (512 blocks) only supplies 2/CU -> latency hiding never materialized
// (268us, msg still ~27us x5 vs ~7us LDS floor).
// r15: msg_k split BY CHANNEL ACROSS 2 BLOCKS (half 0: ch 0-11, half 1:
// ch 12-20 + never-stored zero pads). Per-block microstructure is the
// PROVEN r14 4-wave di-split (r8's pathological axis was waves, not
// blocks) -> per-channel tap order and reduce order bit-identical.
//  * grid 1024 = 4 blocks/CU (matches capacity), 16 waves/CU;
//  * halo LDS 18x18x12 floats = 15.2 KB, stride 12 (8 lanes/bank-quad =
//    the b128 structural minimum, same as r14's stride 28);
//  * g tile read by both halves (+16 MB, L3-resident, ~1us);
//  * acc[12] not acc[21] -> VGPR down, 8-block capacity headroom.
// prep/gauss/combine unchanged from r14. absmax must stay exactly 0.25.

#define BB 2
#define CC 21
#define HH 512
#define WW 512
#define HP 128
#define WP 128
#define KF 11
#define SPAN 5
#define NB 121
#define NITER 5
#define PLF (HH*WW)
#define PLP (HP*WP)
#define PC 24      // packed channel stride (floats), 96 B = 6 x float4
#define PSTR2 12   // halo LDS stride (floats) for 3-float4 half-channel tile
#define RSTR2 13   // reduce-buffer lane stride (odd -> conflict-free)
#define PT2_N (18*18*PSTR2)        // 3888 floats = 15.2 KB

// blocks 0..1023: init tiles; blocks 1024..1407: img pool.
__global__ __launch_bounds__(256) void prep_k(const float* __restrict__ img,
                                              const float* __restrict__ col_schan,
                                              const float* __restrict__ unary,
                                              float* __restrict__ cf,
                                              float* __restrict__ p) {
    int bid = blockIdx.x;
    int t = threadIdx.x;
    if (bid >= 1024) {                       // ---- pool img -> cf ----
        int idx = (bid - 1024)*256 + t;      // < BB*3*PLP = 98304 exactly
        int Y  = idx & (WP-1);
        int X  = (idx >> 7) & (HP-1);
        int bc = idx >> 14;
        const float* base = img + ((size_t)bc*HH + X*4)*WW + Y*4;
        float s = 0.f;
        #pragma unroll
        for (int i = 0; i < 4; ++i)
            #pragma unroll
            for (int j = 0; j < 4; ++j)
                s += base[i*WW + j];
        cf[idx] = s * (1.f/16.f) * col_schan[0];
        return;
    }
    // ---- p0 = 4x4 pool of log_softmax(unary), packed [b][X][Y][24] ----
    int b = bid >> 9, rem = bid & 511, tx = rem >> 4, ty = rem & 15;
    int row = t >> 4, c2 = t & 15;
    int x = tx*16 + row, y = ty*32 + 2*c2;
    size_t base = (size_t)b*CC*PLF + (size_t)x*WW + y;
    float va[CC], vb[CC];
    float ma = -1e30f, mb = -1e30f;
    #pragma unroll
    for (int c = 0; c < CC; ++c) {
        float2 u = *(const float2*)(unary + base + (size_t)c*PLF);
        va[c] = u.x; vb[c] = u.y;
        ma = fmaxf(ma, u.x); mb = fmaxf(mb, u.y);
    }
    float sa = 0.f, sb = 0.f;
    #pragma unroll
    for (int c = 0; c < CC; ++c) { sa += expf(va[c]-ma); sb += expf(vb[c]-mb); }
    float lsa = ma + logf(sa), lsb = mb + logf(sb);
    float out[PC];
    #pragma unroll
    for (int c = 0; c < PC; ++c) out[c] = 0.f;
    #pragma unroll
    for (int c = 0; c < CC; ++c) {
        float sm = (va[c]-lsa) + (vb[c]-lsb);
        sm += __shfl_xor(sm, 1);
        sm += __shfl_xor(sm, 16);
        sm += __shfl_xor(sm, 32);
        out[c] = sm * (1.f/16.f);
    }
    int lane = t & 63;
    if ((lane & 49) == 0) {                  // bits {0,4,5} == 0
        int X = tx*4 + (t >> 6), Y = ty*8 + (c2 >> 1);
        float4* dst = (float4*)(p + ((size_t)(b*HP + X)*WP + Y)*PC);
        const float4* src = (const float4*)out;
        dst[0]=src[0]; dst[1]=src[1]; dst[2]=src[2];
        dst[3]=src[3]; dst[4]=src[4]; dst[5]=src[5];
    }
}

// g block-tiled: g[((b*16+tX)*16+tY)*121*64 + ij*64 + pos], pos = 8x8 tile.
__global__ void gauss_k(const float* __restrict__ cf,
                        const float* __restrict__ pos_sdims,
                        const float* __restrict__ pos_compat,
                        const float* __restrict__ col_compat,
                        float* __restrict__ g) {
    int tile = blockIdx.y;
    int e = blockIdx.x * blockDim.x + threadIdx.x;
    if (e >= NB*64) return;
    int pos = e & 63;
    int ij  = e >> 6;
    int tY = tile & 15, tX = (tile >> 4) & 15, b = tile >> 8;
    int X = tX*8 + (pos >> 3), Y = tY*8 + (pos & 7);
    int di = ij / KF - SPAN;
    int dj = ij % KF - SPAN;
    int Xn = X + di, Yn = Y + dj;
    float val = 0.f;
    if (Xn >= 0 && Xn < HP && Yn >= 0 && Yn < WP) {
        const float* cb = cf + (size_t)b*3*PLP;
        int o0 = X*WP + Y, o = Xn*WP + Yn;
        float d0 = cb[o]         - cb[o0];
        float d1 = cb[PLP + o]   - cb[PLP + o0];
        float d2 = cb[2*PLP + o] - cb[2*PLP + o0];
        float cd2 = d0*d0 + d1*d1 + d2*d2;
        float ps  = 4.f * pos_sdims[0];
        float pd2 = ps*ps * (float)(di*di + dj*dj);
        val = pos_compat[0] * expf(-0.5f*pd2) + col_compat[0] * expf(-0.5f*cd2);
    }
    g[(size_t)tile*NB*64 + e] = val;
}

// msg[b,c,X,Y] = sum_ij g[b,ij,X,Y] * p_packed[b,X+di-5,Y+dj-5,c]
// grid (16,16,4): z = b*2 + half; half 0 -> ch 0-11, half 1 -> ch 12-20.
// 256 thr = 4 waves, channel-major within half; wave w owns di rows
// {0-2,3-5,6-8,9-10}; rbuf overlaid on pt. Tap & reduce order == r14.
__global__ __launch_bounds__(256) void msg_k(const float* __restrict__ g,
                                             const float* __restrict__ p,
                                             float* __restrict__ msg) {
    int zz = blockIdx.z, tx = blockIdx.y, ty = blockIdx.x;
    int b = zz >> 1, half = zz & 1;
    int koff = half*3, coff = half*12;
    int t = threadIdx.x;
    __shared__ __align__(16) float sh[PT2_N];          // 15.2 KB
    float* pt = sh;
    int X0 = tx*8 - SPAN, Y0 = ty*8 - SPAN;
    const float4* pg = (const float4*)(p + (size_t)b*PLP*PC);
    for (int e = t; e < 18*18*3; e += 256) {
        int pos = e / 3, k = e % 3;
        int r = pos / 18, cl = pos % 18;
        int gX = X0 + r, gY = Y0 + cl;
        float4 v = {0.f,0.f,0.f,0.f};
        if (gX >= 0 && gX < HP && gY >= 0 && gY < WP)
            v = pg[(size_t)(gX*WP + gY)*6 + k + koff];
        *(float4*)(pt + pos*PSTR2 + k*4) = v;
    }
    __syncthreads();
    int w = t >> 6, lane = t & 63;
    int x = lane >> 3, y = lane & 7;
    const float* gt = g + (size_t)((b*16 + tx)*16 + ty)*NB*64 + lane;
    int d0 = w*3, d1 = (w == 3) ? KF : w*3 + 3;        // {0-2,3-5,6-8,9-10}
    float acc[12];
    #pragma unroll
    for (int c = 0; c < 12; ++c) acc[c] = 0.f;
    for (int di = d0; di < d1; ++di) {
        const float* prow = pt + ((x+di)*18 + y)*PSTR2;
        const float* grow = gt + (size_t)(di*KF)*64;
        #pragma unroll
        for (int dj = 0; dj < KF; ++dj) {
            float gv = grow[(size_t)dj*64];
            const float4* sp = (const float4*)(prow + dj*PSTR2);
            float4 q0 = sp[0], q1 = sp[1], q2 = sp[2];
            acc[0]  = fmaf(gv, q0.x, acc[0]);  acc[1]  = fmaf(gv, q0.y, acc[1]);
            acc[2]  = fmaf(gv, q0.z, acc[2]);  acc[3]  = fmaf(gv, q0.w, acc[3]);
            acc[4]  = fmaf(gv, q1.x, acc[4]);  acc[5]  = fmaf(gv, q1.y, acc[5]);
            acc[6]  = fmaf(gv, q1.z, acc[6]);  acc[7]  = fmaf(gv, q1.w, acc[7]);
            acc[8]  = fmaf(gv, q2.x, acc[8]);  acc[9]  = fmaf(gv, q2.y, acc[9]);
            acc[10] = fmaf(gv, q2.z, acc[10]); acc[11] = fmaf(gv, q2.w, acc[11]);
        }
    }
    __syncthreads();                       // all pt reads done before overlay
    float* rb = sh;                        // rbuf [3][64][RSTR2] overlays pt
    if (w > 0) {
        #pragma unroll
        for (int c = 0; c < 12; ++c) rb[((w-1)*64 + lane)*RSTR2 + c] = acc[c];
    }
    __syncthreads();
    if (w == 0) {
        int Xg = tx*8 + x, Yg = ty*8 + y;
        float* mb = msg + (size_t)b*CC*PLP + (size_t)Xg*WP + Yg;
        int nst = half ? 9 : 12;           // half1: ch 21-23 are pads
        for (int c = 0; c < nst; ++c) {
            float s = ((acc[c] + rb[(0*64 + lane)*RSTR2 + c])
                              + rb[(1*64 + lane)*RSTR2 + c])
                              + rb[(2*64 + lane)*RSTR2 + c];
            mb[(size_t)(coff + c)*PLP] = s;
        }
    }
}

// bilinear 4x upsample of msg + 0.8*lg + 0.2*mu; iters 0..3: softmax + 4x4
// pool -> packed p; last iter: write fp32 pred. 2 pixels per thread.
__global__ __launch_bounds__(256) void combine_k(const float* __restrict__ msg,
                                                 const float* __restrict__ unary,
                                                 const float* __restrict__ weight,
                                                 float* __restrict__ pnew,
                                                 float* __restrict__ pred,
                                                 int last) {
    int b = blockIdx.z, tx = blockIdx.y, ty = blockIdx.x;
    int t = threadIdx.x;
    __shared__ float ms[CC][6][10];
    const float* mb = msg + (size_t)b*CC*PLP;
    for (int e = t; e < CC*60; e += 256) {
        int c = e / 60, rr = (e / 10) % 6, cl = e % 10;
        int gX = tx*4 - 1 + rr; gX = gX < 0 ? 0 : (gX > HP-1 ? HP-1 : gX);
        int gY = ty*8 - 1 + cl; gY = gY < 0 ? 0 : (gY > WP-1 ? WP-1 : gY);
        ms[c][rr][cl] = mb[(size_t)c*PLP + gX*WP + gY];
    }
    __syncthreads();
    int row = t >> 4, c2 = t & 15;
    int x = tx*16 + row, y = ty*32 + 2*c2;
    size_t base = (size_t)b*CC*PLF + (size_t)x*WW + y;
    // bilinear: fx per (x%4): {0.625, 0.875, 0.125, 0.375}
    int rs = row & 3, q = row >> 2;
    float fx = (rs == 0) ? 0.625f : (rs == 1) ? 0.875f : (rs == 2) ? 0.125f : 0.375f;
    int i0 = q + (rs >> 1);
    int cs0 = (2*c2) & 3;                    // 0 or 2; pixel pair shares j0
    int qc  = (2*c2) >> 2;
    float fya = (cs0 == 0) ? 0.625f : 0.125f;
    float fyb = (cs0 == 0) ? 0.875f : 0.375f;
    int j0 = qc + (cs0 >> 1);
    float gx0 = 1.f - fx;
    float wt = weight[0], uw = 1.f - wt;     // UNARY_WEIGHT = 1.0
    float va[CC], vb[CC];
    float ma = -1e30f, mbx = -1e30f;
    #pragma unroll
    for (int c = 0; c < CC; ++c) {
        float2 u = *(const float2*)(unary + base + (size_t)c*PLF);
        va[c] = u.x; vb[c] = u.y;
        ma = fmaxf(ma, u.x); mbx = fmaxf(mbx, u.y);
    }
    float sa = 0.f, sb = 0.f;
    #pragma unroll
    for (int c = 0; c < CC; ++c) { sa += expf(va[c]-ma); sb += expf(vb[c]-mbx); }
    float lsa = ma + logf(sa), lsb = mbx + logf(sb);
    #pragma unroll
    for (int c = 0; c < CC; ++c) {
        float m00 = ms[c][i0][j0],   m01 = ms[c][i0][j0+1];
        float m10 = ms[c][i0+1][j0], m11 = ms[c][i0+1][j0+1];
        float ca = gx0*m00 + fx*m10;         // column j0 blended in x
        float cb = gx0*m01 + fx*m11;         // column j0+1 blended in x
        float mua = (1.f-fya)*ca + fya*cb;
        float mub = (1.f-fyb)*ca + fyb*cb;
        va[c] = uw*(va[c]-lsa) + wt*mua;
        vb[c] = uw*(vb[c]-lsb) + wt*mub;
    }
    if (last) {
        #pragma unroll
        for (int c = 0; c < CC; ++c) {
            float2 o; o.x = va[c]; o.y = vb[c];
            *(float2*)(pred + base + (size_t)c*PLF) = o;
        }
    } else {
        float mma = -1e30f, mmb = -1e30f;
        #pragma unroll
        for (int c = 0; c < CC; ++c) { mma = fmaxf(mma, va[c]); mmb = fmaxf(mmb, vb[c]); }
        float ssa = 0.f, ssb = 0.f;
        #pragma unroll
        for (int c = 0; c < CC; ++c) {
            va[c] = expf(va[c]-mma); ssa += va[c];
            vb[c] = expf(vb[c]-mmb); ssb += vb[c];
        }
        float ia = 1.f/ssa, ib = 1.f/ssb;
        float out[PC];
        #pragma unroll
        for (int c = 0; c < PC; ++c) out[c] = 0.f;
        #pragma unroll
        for (int c = 0; c < CC; ++c) {
            float sm = va[c]*ia + vb[c]*ib;
            sm += __shfl_xor(sm, 1);
            sm += __shfl_xor(sm, 16);
            sm += __shfl_xor(sm, 32);
            out[c] = sm * (1.f/16.f);
        }
        int lane = t & 63;
        if ((lane & 49) == 0) {
            int X = tx*4 + (t >> 6), Y = ty*8 + (c2 >> 1);
            float4* dst = (float4*)(pnew + ((size_t)(b*HP + X)*WP + Y)*PC);
            const float4* src = (const float4*)out;
            dst[0]=src[0]; dst[1]=src[1]; dst[2]=src[2];
            dst[3]=src[3]; dst[4]=src[4]; dst[5]=src[5];
        }
    }
}

extern "C" void kernel_launch(void* const* d_in, const int* in_sizes, int n_in,
                              void* d_out, int out_size, void* d_ws, size_t ws_size,
                              hipStream_t stream) {
    const float* unary      = (const float*)d_in[0];
    const float* img        = (const float*)d_in[1];
    const float* pos_sdims  = (const float*)d_in[2];
    const float* col_schan  = (const float*)d_in[3];
    const float* pos_compat = (const float*)d_in[4];
    const float* col_compat = (const float*)d_in[5];
    const float* weight     = (const float*)d_in[6];
    float* pred = (float*)d_out;
    float* ws   = (float*)d_ws;

    size_t o = 0;
    float* cf  = ws + o;  o += (size_t)BB*3*PLP;     // 0.4 MB
    float* g   = ws + o;  o += (size_t)BB*NB*PLP;    // 15.9 MB (tiled)
    float* msg = ws + o;  o += (size_t)BB*CC*PLP;    // 2.75 MB
    float* pA  = ws + o;  o += (size_t)BB*PLP*PC;    // 3.1 MB packed
    float* pB  = ws + o;
    float* pbuf[2] = {pA, pB};

    const int TB = 256;
    hipLaunchKernelGGL(prep_k, dim3(1408), dim3(TB), 0, stream,
                       img, col_schan, unary, cf, pA);
    hipLaunchKernelGGL(gauss_k, dim3((NB*64+TB-1)/TB, 512), dim3(TB), 0, stream,
                       cf, pos_sdims, pos_compat, col_compat, g);
    for (int it = 0; it < NITER; ++it) {
        hipLaunchKernelGGL(msg_k, dim3(16, 16, BB*2), dim3(256), 0, stream,
                           g, pbuf[it & 1], msg);
        hipLaunchKernelGGL(combine_k, dim3(16, 32, BB), dim3(256), 0, stream,
                           msg, unary, weight, pbuf[(it + 1) & 1],
                           pred, (it == NITER-1) ? 1 : 0);
    }
}